// Round 1
// baseline (333.109 us; speedup 1.0000x reference)
//
#include <hip/hip_runtime.h>
#include <stdint.h>
#include <math.h>

#define N_ROWS 16384
#define D_DIM  4096
#define E_EXP  128
#define BM     32
#define BK     32
#define NTILES (D_DIM / BK)   // 128

#define GAS __attribute__((address_space(1)))
#define LAS __attribute__((address_space(3)))

__device__ __forceinline__ void g2lds16(const float* g, float* l) {
  __builtin_amdgcn_global_load_lds((const GAS uint32_t*)g, (LAS uint32_t*)l, 16, 0, 0);
}

// strict total order: conf desc, then logit desc, then index asc
__device__ __forceinline__ bool cand_gt(float ca, double la, int ia,
                                        float cb, double lb, int ib) {
  if (ca != cb) return ca > cb;
  if (la != lb) return la > lb;
  return ia < ib;
}

struct Top2 { float c0, c1; double l0, l1; int i0, i1; };

__device__ __forceinline__ void top2_ins(Top2& s, float c, double l, int i) {
  if (cand_gt(c, l, i, s.c0, s.l0, s.i0)) {
    s.c1 = s.c0; s.l1 = s.l0; s.i1 = s.i0;
    s.c0 = c;    s.l0 = l;    s.i0 = i;
  } else if (cand_gt(c, l, i, s.c1, s.l1, s.i1)) {
    s.c1 = c;    s.l1 = l;    s.i1 = i;
  }
}

__global__ __launch_bounds__(256) void gate_kernel(
    const float* __restrict__ x, const float* __restrict__ Wm,
    const float* __restrict__ bias, float* __restrict__ out)
{
  // LDS: Xs [2][32][32] f32 (8 KiB) | Ws [2][128][32] f32 (32 KiB)  = 40 KiB
  __shared__ __align__(16) uint8_t smem[40960];
  float*  Xs = (float*)smem;
  float*  Ws = (float*)(smem + 8192);
  // epilogue overlay (on Xs region, used only after final barrier):
  float*  Rc = (float*)smem;            // [128][2]
  double* Rl = (double*)(smem + 1024);  // [128][2]
  int*    Ri = (int*)(smem + 3072);     // [128][2]

  const int t    = threadIdx.x;
  const int wv   = t >> 6;      // wave 0..3 -> cols [32*wv, 32*wv+32)
  const int lane = t & 63;
  const int mg   = lane >> 3;   // row group 0..7 (4 rows each)
  const int cg   = lane & 7;    // col group 0..7 (4 cols each)
  const int row0 = blockIdx.x * BM;

  double acc64[4][4];
  #pragma unroll
  for (int i = 0; i < 4; ++i)
    #pragma unroll
    for (int j = 0; j < 4; ++j) acc64[i][j] = 0.0;

  // ---- staging descriptors (granule = 16 B = 4 floats) ----
  // X: 256 granules/tile, chunk c = t: row=c>>3, pos p=c&7 holds data granule p^((row>>2)&7)
  const int xrow = t >> 3, xp = t & 7;
  const int xgd  = xp ^ ((xrow >> 2) & 7);
  const float* xsrc = x + (size_t)(row0 + xrow) * D_DIM + xgd * 4;

  auto stage = [&](int buf, int kt) {
    const int koff = kt * BK;
    g2lds16(xsrc + koff, Xs + buf * 1024 + t * 4);
    #pragma unroll
    for (int i = 0; i < 4; ++i) {         // W: 1024 granules/tile, 4 per thread
      int c = t + 256 * i;
      int e = c >> 3, p = c & 7;
      int gd = p ^ ((e >> 2) & 7);
      g2lds16(Wm + (size_t)e * D_DIM + koff + gd * 4,
              Ws + buf * 4096 + c * 4);
    }
  };

  stage(0, 0);

  for (int kt = 0; kt < NTILES; ++kt) {
    const int cur = kt & 1;
    if (kt + 1 < NTILES) {
      stage(cur ^ 1, kt + 1);
      asm volatile("s_waitcnt vmcnt(5)" ::: "memory");  // wait current tile only
    } else {
      asm volatile("s_waitcnt vmcnt(0)" ::: "memory");
    }
    __builtin_amdgcn_s_barrier();

    const float* Xb = Xs + cur * 1024;
    const float* Wb = Ws + cur * 4096;

    float acc[4][4];
    #pragma unroll
    for (int i = 0; i < 4; ++i)
      #pragma unroll
      for (int j = 0; j < 4; ++j) acc[i][j] = 0.f;

    #pragma unroll
    for (int g = 0; g < 8; ++g) {         // 4 d-values per chunk
      float4 av[4], bv[4];
      #pragma unroll
      for (int i = 0; i < 4; ++i) {
        int r = mg * 4 + i;
        av[i] = *(const float4*)(Xb + r * BK + ((g ^ mg) & 7) * 4);
      }
      #pragma unroll
      for (int j = 0; j < 4; ++j) {
        int e = wv * 32 + cg * 4 + j;
        bv[j] = *(const float4*)(Wb + e * BK + ((g ^ cg) & 7) * 4);
      }
      #pragma unroll
      for (int i = 0; i < 4; ++i)
        #pragma unroll
        for (int j = 0; j < 4; ++j) {
          acc[i][j] = fmaf(av[i].w, bv[j].w,
                      fmaf(av[i].z, bv[j].z,
                      fmaf(av[i].y, bv[j].y,
                      fmaf(av[i].x, bv[j].x, acc[i][j]))));
        }
    }
    #pragma unroll
    for (int i = 0; i < 4; ++i)
      #pragma unroll
      for (int j = 0; j < 4; ++j) acc64[i][j] += (double)acc[i][j];

    asm volatile("" ::: "memory");        // keep LDS reads above barrier
    __builtin_amdgcn_s_barrier();
  }

  // ---- epilogue: sigmoid (f64) + top-2 ----
  #pragma unroll
  for (int i = 0; i < 4; ++i) {
    Top2 s;
    s.c0 = s.c1 = -1.0f; s.l0 = s.l1 = -1.0e300; s.i0 = s.i1 = 0x7fffffff;
    #pragma unroll
    for (int j = 0; j < 4; ++j) {
      int e = wv * 32 + cg * 4 + j;
      double lg = acc64[i][j] + (double)bias[e];
      float cf = (float)(1.0 / (1.0 + exp(-lg)));
      top2_ins(s, cf, lg, e);
    }
    #pragma unroll
    for (int m = 1; m <= 4; m <<= 1) {    // butterfly over the 8 col-groups
      float  oc0 = __shfl_xor(s.c0, m), oc1 = __shfl_xor(s.c1, m);
      double ol0 = __shfl_xor(s.l0, m), ol1 = __shfl_xor(s.l1, m);
      int    oi0 = __shfl_xor(s.i0, m), oi1 = __shfl_xor(s.i1, m);
      top2_ins(s, oc0, ol0, oi0);
      top2_ins(s, oc1, ol1, oi1);
    }
    if (cg == 0) {                        // wave-local top2 of 32 cols for this row
      int ridx = wv * 32 + mg * 4 + i;
      Rc[ridx * 2 + 0] = s.c0; Rc[ridx * 2 + 1] = s.c1;
      Rl[ridx * 2 + 0] = s.l0; Rl[ridx * 2 + 1] = s.l1;
      Ri[ridx * 2 + 0] = s.i0; Ri[ridx * 2 + 1] = s.i1;
    }
  }
  __syncthreads();

  if (t < BM) {                           // merge 4 wave results per row
    Top2 s;
    s.c0 = s.c1 = -1.0f; s.l0 = s.l1 = -1.0e300; s.i0 = s.i1 = 0x7fffffff;
    #pragma unroll
    for (int w2 = 0; w2 < 4; ++w2) {
      int ei = w2 * 32 + t;
      top2_ins(s, Rc[ei * 2 + 0], Rl[ei * 2 + 0], Ri[ei * 2 + 0]);
      top2_ins(s, Rc[ei * 2 + 1], Rl[ei * 2 + 1], Ri[ei * 2 + 1]);
    }
    int grow = row0 + t;
    out[(size_t)grow * 2 + 0] = s.c0;
    out[(size_t)grow * 2 + 1] = s.c1;
    out[(size_t)N_ROWS * 2 + (size_t)grow * 2 + 0] = (float)s.i0;
    out[(size_t)N_ROWS * 2 + (size_t)grow * 2 + 1] = (float)s.i1;
  }
}

extern "C" void kernel_launch(void* const* d_in, const int* in_sizes, int n_in,
                              void* d_out, int out_size, void* d_ws, size_t ws_size,
                              hipStream_t stream) {
  const float* x  = (const float*)d_in[0];
  const float* Wm = (const float*)d_in[1];
  const float* b  = (const float*)d_in[2];
  float* out = (float*)d_out;
  dim3 grid(N_ROWS / BM);   // 512 blocks
  dim3 block(256);
  gate_kernel<<<grid, block, 0, stream>>>(x, Wm, b, out);
}